// Round 5
// baseline (214.578 us; speedup 1.0000x reference)
//
#include <hip/hip_runtime.h>

// VectorQuantizer: x (32,64,64,64) f32, codebook (1024,64) f32
// out = concat( quantized (32,64,64,64) f32 , indices (32,64,64) as f32 )
//
// R5: MFMA-bound restructure of R4 (which was VALU-issue-bound: 300 VALU vs
// 12 MFMA per tile).
//  - cn folded into MFMA C-operand (acm = cn - 2*dot directly); B streams
//    pre-scaled by -2 in prep. No per-tile zero-init, no dist fma.
//  - top-2 via v_med3_f32: 4 VALU per C-element, no bit-packing (exact f32).
//  - M=64 positions/wave (4 tiles): 24 MFMA/ct vs ~100 VALU/ct -> MFMA pole;
//    halves per-wave B-stream L2 traffic vs M=32.
//  - rescan fused in-wave (quad-divergent exact-f32 path, EPS=0.01 with 66x
//    margin over the 1.5e-4 split-error bound) -> only 2 dispatches total.
//
// Fragment layouts verified end-to-end by R4 (absmax 0):
//   A: lane holds A[m=lane&15][k=(lane>>4)*8+j];  B: B[k][n=lane&15] same;
//   C/D: col=lane&15, row=(lane>>4)*4+reg.

typedef _Float16 f16x8 __attribute__((ext_vector_type(8)));
typedef float    f32x4 __attribute__((ext_vector_type(4)));

#define VQ_D    64
#define VQ_HW   4096
#define VQ_NPOS 131072
#define SC      2048.0f
#define ISC     (1.0f / 2048.0f)
#define EPS     0.01f
#define WS_CBN  65536      // float offset of cn[1024] (bp = 16384 f16x8 = 256 KB)

// ---------- prep: pack scaled B-fragment streams + exact f32 norms ----------
// bp item layout: it = (ct*4 + s)*64 + lane, s: 0=bh2 ks0, 1=bh2 ks1,
// 2=rb2k ks0, 3=rb2k ks1.  bh2 = -2*f16(b) (exact), rb2k = f16(-2*SC*(b-bh)).
__global__ __launch_bounds__(256)
void vq_prep(const float* __restrict__ cb, float* __restrict__ ws)
{
    const int tid = threadIdx.x;
    if (blockIdx.x < 64) {
        const int it   = blockIdx.x * 256 + tid;     // [0, 16384)
        const int ct   = it >> 8;
        const int s    = (it >> 6) & 3;
        const int lane = it & 63;
        const int ks   = s & 1, isR = s >> 1;
        const int n    = ct * 16 + (lane & 15);
        const int k0   = ks * 32 + (lane >> 4) * 8;
        const float* src = cb + n * 64 + k0;
        f16x8 o;
        #pragma unroll
        for (int j = 0; j < 8; ++j) {
            const float b = src[j];
            const _Float16 bh = (_Float16)b;
            o[j] = isR ? (_Float16)((b - (float)bh) * (-2.0f * SC))
                       : (_Float16)(-2.0f * (float)bh);
        }
        ((f16x8*)ws)[it] = o;
    } else {
        const int k = (blockIdx.x - 64) * 256 + tid; // [0, 1024)
        const float4* row = (const float4*)(cb + k * 64);
        float a0 = 0.f, a1 = 0.f, a2 = 0.f, a3 = 0.f;
        #pragma unroll
        for (int j = 0; j < 16; ++j) {
            const float4 c = row[j];
            a0 = fmaf(c.x, c.x, a0); a1 = fmaf(c.y, c.y, a1);
            a2 = fmaf(c.z, c.z, a2); a3 = fmaf(c.w, c.w, a3);
        }
        ws[WS_CBN + k] = (a0 + a1) + (a2 + a3);
    }
}

// ---------- main ----------
__global__ __launch_bounds__(256, 2)
void vq_main(const float* __restrict__ x,
             const float* __restrict__ cb,
             const float* __restrict__ ws,
             float* __restrict__ out,
             float* __restrict__ idx_out)
{
    __shared__ int   sk[256];
    __shared__ float rxs[4][4][VQ_D];     // [wave][quad][dim] rescan stage

    const int tid  = threadIdx.x;
    const int lane = tid & 63;
    const int wv   = tid >> 6;
    const int m    = lane & 15;
    const int q    = lane >> 4;

    const f16x8* bp  = (const f16x8*)ws;
    const float* cnb = ws + WS_CBN;

    const int p0 = blockIdx.x * 256;      // block: 256 consecutive positions
    const int b  = p0 >> 12;
    const int n0 = p0 & (VQ_HW - 1);
    const float* xw = x + (size_t)b * (VQ_D * VQ_HW) + n0 + wv * 64;

    // ---- A fragments: hi + scaled residual, 4 M-tiles, resident ----
    f16x8 Ah[4][2], Ra[4][2];
    #pragma unroll
    for (int tl = 0; tl < 4; ++tl)
        #pragma unroll
        for (int ks = 0; ks < 2; ++ks) {
            f16x8 h8, r8;
            #pragma unroll
            for (int j = 0; j < 8; ++j) {
                const int k = ks * 32 + q * 8 + j;
                const float v = xw[(size_t)k * VQ_HW + tl * 16 + m];
                const _Float16 vh = (_Float16)v;
                h8[j] = vh;
                r8[j] = (_Float16)((v - (float)vh) * SC);
            }
            Ah[tl][ks] = h8; Ra[tl][ks] = r8;
        }

    float d1[4][4], d2[4][4]; int k1[4][4];
    #pragma unroll
    for (int tl = 0; tl < 4; ++tl)
        #pragma unroll
        for (int r = 0; r < 4; ++r) { d1[tl][r] = 3.4e38f; d2[tl][r] = 3.4e38f; k1[tl][r] = 0; }

    const f32x4 zero4 = {0.f, 0.f, 0.f, 0.f};

    // preload ct=0 streams
    f16x8 B0 = bp[lane], B1 = bp[64 + lane], R0 = bp[128 + lane], R1 = bp[192 + lane];
    float cv = cnb[m];

    for (int ct = 0; ct < 64; ++ct) {
        // prefetch ct+1 (clamped; duplicate final load harmless)
        f16x8 nB0, nB1, nR0, nR1; float ncv;
        {
            const int ctn = (ct < 63) ? ct + 1 : 63;
            const f16x8* base = bp + ctn * 256;
            nB0 = base[lane];       nB1 = base[64 + lane];
            nR0 = base[128 + lane]; nR1 = base[192 + lane];
            ncv = cnb[ctn * 16 + m];
        }

        const f32x4 Ci = {cv, cv, cv, cv};
        f32x4 acm[4], acc[4];
        #pragma unroll
        for (int tl = 0; tl < 4; ++tl) {
            acm[tl] = __builtin_amdgcn_mfma_f32_16x16x32_f16(Ah[tl][0], B0, Ci,      0, 0, 0);
            acm[tl] = __builtin_amdgcn_mfma_f32_16x16x32_f16(Ah[tl][1], B1, acm[tl], 0, 0, 0);
            acc[tl] = __builtin_amdgcn_mfma_f32_16x16x32_f16(Ah[tl][0], R0, zero4,   0, 0, 0);
            acc[tl] = __builtin_amdgcn_mfma_f32_16x16x32_f16(Ah[tl][1], R1, acc[tl], 0, 0, 0);
            acc[tl] = __builtin_amdgcn_mfma_f32_16x16x32_f16(Ra[tl][0], B0, acc[tl], 0, 0, 0);
            acc[tl] = __builtin_amdgcn_mfma_f32_16x16x32_f16(Ra[tl][1], B1, acc[tl], 0, 0, 0);
        }

        const int code = ct * 16 + m;
        #pragma unroll
        for (int tl = 0; tl < 4; ++tl)
            #pragma unroll
            for (int r = 0; r < 4; ++r) {
                const float dist = fmaf(acc[tl][r], ISC, acm[tl][r]); // = cn - 2*dot
                const float od   = d1[tl][r];
                const bool  c    = dist < od;                          // strict <: first-min
                d2[tl][r] = __builtin_amdgcn_fmed3f(dist, od, d2[tl][r]);
                d1[tl][r] = c ? dist : od;
                k1[tl][r] = c ? code : k1[tl][r];
            }

        B0 = nB0; B1 = nB1; R0 = nR0; R1 = nR1; cv = ncv;
    }

    // ---- top-2 merge across the 16 code-columns (xor 1,2,4,8) ----
    #pragma unroll
    for (int off = 1; off < 16; off <<= 1)
        #pragma unroll
        for (int tl = 0; tl < 4; ++tl)
            #pragma unroll
            for (int r = 0; r < 4; ++r) {
                const float od1 = __shfl_xor(d1[tl][r], off, 64);
                const float od2 = __shfl_xor(d2[tl][r], off, 64);
                const int   ok1 = __shfl_xor(k1[tl][r], off, 64);
                const float nd2 = fminf(fmaxf(d1[tl][r], od1), fminf(d2[tl][r], od2));
                const bool  sw  = (od1 < d1[tl][r]) ||
                                  (od1 == d1[tl][r] && ok1 < k1[tl][r]); // tie -> min k
                d1[tl][r] = sw ? od1 : d1[tl][r];
                k1[tl][r] = sw ? ok1 : k1[tl][r];
                d2[tl][r] = nd2;
            }

    // ---- rare exact-f32 in-wave rescan when gap < EPS (quad-uniform cond) ----
    #pragma unroll 1
    for (int tl = 0; tl < 4; ++tl)
        #pragma unroll 1
        for (int r = 0; r < 4; ++r) {
            if (d2[tl][r] - d1[tl][r] < EPS) {
                const int p  = p0 + wv * 64 + tl * 16 + q * 4 + r;
                const int nn = p & (VQ_HW - 1);
                #pragma unroll
                for (int u = 0; u < 4; ++u)
                    rxs[wv][q][m * 4 + u] =
                        x[(size_t)b * (VQ_D * VQ_HW) + (size_t)(m * 4 + u) * VQ_HW + nn];
                float bd = 3.4e38f; int bk2 = 0;
                for (int t = 0; t < 64; ++t) {
                    const int code = t * 16 + m;              // ascending per lane
                    const float* row = cb + (size_t)code * VQ_D;
                    float a0 = 0.f, a1 = 0.f, a2 = 0.f, a3 = 0.f;
                    #pragma unroll
                    for (int dd = 0; dd < VQ_D; dd += 4) {
                        a0 = fmaf(rxs[wv][q][dd + 0], row[dd + 0], a0);
                        a1 = fmaf(rxs[wv][q][dd + 1], row[dd + 1], a1);
                        a2 = fmaf(rxs[wv][q][dd + 2], row[dd + 2], a2);
                        a3 = fmaf(rxs[wv][q][dd + 3], row[dd + 3], a3);
                    }
                    const float dist = fmaf(-2.0f, (a0 + a1) + (a2 + a3), cnb[code]);
                    if (dist < bd) { bd = dist; bk2 = code; }
                }
                #pragma unroll
                for (int off = 1; off < 16; off <<= 1) {      // intra-quad exact merge
                    const float od = __shfl_xor(bd, off, 64);
                    const int   ok = __shfl_xor(bk2, off, 64);
                    if (od < bd || (od == bd && ok < bk2)) { bd = od; bk2 = ok; }
                }
                k1[tl][r] = bk2;
            }
        }

    if (m == 0) {
        #pragma unroll
        for (int tl = 0; tl < 4; ++tl)
            #pragma unroll
            for (int r = 0; r < 4; ++r)
                sk[wv * 64 + tl * 16 + q * 4 + r] = k1[tl][r];
    }
    __syncthreads();

    // ---- epilogue: indices + quantized scatter (coalesced over n) ----
    idx_out[p0 + tid] = (float)sk[tid];
    const int bk = sk[tid];
    const float4* cr = (const float4*)(cb + (size_t)bk * VQ_D);
    float* ob = out + (size_t)b * (VQ_D * VQ_HW) + n0 + tid;
    #pragma unroll
    for (int d4 = 0; d4 < 16; ++d4) {
        const float4 v = cr[d4];
        ob[(size_t)(d4 * 4 + 0) * VQ_HW] = v.x;
        ob[(size_t)(d4 * 4 + 1) * VQ_HW] = v.y;
        ob[(size_t)(d4 * 4 + 2) * VQ_HW] = v.z;
        ob[(size_t)(d4 * 4 + 3) * VQ_HW] = v.w;
    }
}

extern "C" void kernel_launch(void* const* d_in, const int* in_sizes, int n_in,
                              void* d_out, int out_size, void* d_ws, size_t ws_size,
                              hipStream_t stream) {
    const float* x  = (const float*)d_in[0];
    const float* cb = (const float*)d_in[1];
    float* out = (float*)d_out;
    float* idx = out + (size_t)VQ_NPOS * VQ_D;   // 8,388,608 floats in
    float* ws  = (float*)d_ws;                    // 260 KB used

    vq_prep<<<dim3(68),  dim3(256), 0, stream>>>(cb, ws);
    vq_main<<<dim3(512), dim3(256), 0, stream>>>(x, cb, ws, out, idx);
}

// Round 6
// 162.600 us; speedup vs baseline: 1.3197x; 1.3197x over previous
//
#include <hip/hip_runtime.h>

// VectorQuantizer: x (32,64,64,64) f32, codebook (1024,64) f32
// out = concat( quantized (32,64,64,64) f32 , indices (32,64,64) as f32 )
//
// R6 = R5's math (verified absmax 0) without R5's scratch disaster.
//  - R5 post-mortem: '#pragma unroll 1' fused-rescan loops dynamically indexed
//    d1/k1 register arrays -> compiler demoted them to scratch (WRITE_SIZE
//    96 MB, VGPR=88, latency-bound 152 us). R6: NO dynamic indexing; rescan is
//    a separate fast kernel (lanes=codes over transposed codebook).
//  - ct-loop unrolled by 2 with ping-pong B-register sets (no per-iter copies).
//  - M=64 positions/wave, 4 waves/block read the SAME B stream -> L1 dedup,
//    ~268 MB from L2 (~25 TB/s at the predicted 10-15 us main).
//  - cn folded into MFMA C operand; B pre-scaled by -2; top-2 via med3.

typedef _Float16 f16x8 __attribute__((ext_vector_type(8)));
typedef float    f32x4 __attribute__((ext_vector_type(4)));

#define VQ_D    64
#define VQ_HW   4096
#define VQ_NPOS 131072
#define SC      2048.0f
#define ISC     (1.0f / 2048.0f)
#define EPS     2.0e-3f
#define WS_CBN  65536      // f32 cn[1024]           (bp = 16384 f16x8 = 256 KB before it)
#define WS_CBT  66560      // float4 cbT4[16384]     (256 KB)
#define WS_CNT  132096     // int rescan counter
#define WS_LIST 132100     // int list[131072]

// ---------- prep ----------
// bp item: it=(ct*4+s)*64+lane; s: 0=bh2 ks0, 1=bh2 ks1, 2=rb2k ks0, 3=rb2k ks1
// bh2 = -2*f16(b) (exact), rb2k = f16(-2*SC*(b - bh)).
__global__ __launch_bounds__(256)
void vq_prep(const float* __restrict__ cb, float* __restrict__ ws)
{
    const int tid = threadIdx.x;
    const int blk = blockIdx.x;
    if (blk < 64) {
        const int it   = blk * 256 + tid;            // [0, 16384)
        const int ct   = it >> 8;
        const int s    = (it >> 6) & 3;
        const int lane = it & 63;
        const int ks   = s & 1, isR = s >> 1;
        const int n    = ct * 16 + (lane & 15);      // code (B column)
        const int k0   = ks * 32 + (lane >> 4) * 8;  // dim  (B row)
        const float* src = cb + n * 64 + k0;
        f16x8 o;
        #pragma unroll
        for (int j = 0; j < 8; ++j) {
            const float b = src[j];
            const _Float16 bh = (_Float16)b;
            o[j] = isR ? (_Float16)((b - (float)bh) * (-2.0f * SC))
                       : (_Float16)(-2.0f * (float)bh);
        }
        ((f16x8*)ws)[it] = o;
    } else if (blk < 128) {
        const int it = (blk - 64) * 256 + tid;       // [0, 16384)
        const int k = it >> 4, j4 = it & 15;
        ((float4*)(ws + WS_CBT))[j4 * 1024 + k] = ((const float4*)cb)[it];
    } else {
        const int k = (blk - 128) * 256 + tid;       // [0, 1024)
        const float4* row = (const float4*)(cb + k * 64);
        float a0 = 0.f, a1 = 0.f, a2 = 0.f, a3 = 0.f;
        #pragma unroll
        for (int j = 0; j < 16; ++j) {
            const float4 c = row[j];
            a0 = fmaf(c.x, c.x, a0); a1 = fmaf(c.y, c.y, a1);
            a2 = fmaf(c.z, c.z, a2); a3 = fmaf(c.w, c.w, a3);
        }
        ws[WS_CBN + k] = (a0 + a1) + (a2 + a3);
        if (k == 0) ((int*)ws)[WS_CNT] = 0;
    }
}

// ---------- main ----------
#define PREFETCH(B0, B1, R0, R1, CV, CTN)                          \
    {                                                              \
        const f16x8* base_ = bp + (CTN) * 256;                     \
        B0 = base_[lane];       B1 = base_[64 + lane];             \
        R0 = base_[128 + lane]; R1 = base_[192 + lane];            \
        CV = cnb[(CTN) * 16 + m];                                  \
    }

#define COMPUTE(B0, B1, R0, R1, CV, CTV)                                                   \
    {                                                                                      \
        const f32x4 Ci = {CV, CV, CV, CV};                                                 \
        f32x4 acm[4], acc[4];                                                              \
        _Pragma("unroll")                                                                  \
        for (int tl = 0; tl < 4; ++tl) {                                                   \
            acm[tl] = __builtin_amdgcn_mfma_f32_16x16x32_f16(Ah[tl][0], B0, Ci,      0,0,0);\
            acm[tl] = __builtin_amdgcn_mfma_f32_16x16x32_f16(Ah[tl][1], B1, acm[tl], 0,0,0);\
            acc[tl] = __builtin_amdgcn_mfma_f32_16x16x32_f16(Ah[tl][0], R0, zero4,   0,0,0);\
            acc[tl] = __builtin_amdgcn_mfma_f32_16x16x32_f16(Ah[tl][1], R1, acc[tl], 0,0,0);\
            acc[tl] = __builtin_amdgcn_mfma_f32_16x16x32_f16(Ra[tl][0], B0, acc[tl], 0,0,0);\
            acc[tl] = __builtin_amdgcn_mfma_f32_16x16x32_f16(Ra[tl][1], B1, acc[tl], 0,0,0);\
        }                                                                                  \
        const int code_ = (CTV) * 16 + m;                                                  \
        _Pragma("unroll")                                                                  \
        for (int tl = 0; tl < 4; ++tl)                                                     \
            _Pragma("unroll")                                                              \
            for (int r = 0; r < 4; ++r) {                                                  \
                const float dist = fmaf(acc[tl][r], ISC, acm[tl][r]);                      \
                const float od   = d1[tl][r];                                              \
                const bool  c    = dist < od;                                              \
                d2[tl][r] = __builtin_amdgcn_fmed3f(dist, od, d2[tl][r]);                  \
                d1[tl][r] = c ? dist : od;                                                 \
                k1[tl][r] = c ? code_ : k1[tl][r];                                         \
            }                                                                              \
    }

__global__ __launch_bounds__(256, 2)
void vq_main(const float* __restrict__ x,
             const float* __restrict__ cb,
             float* __restrict__ ws,
             float* __restrict__ out,
             float* __restrict__ idx_out)
{
    __shared__ int   sk[256];
    __shared__ float smg[256];

    const int tid  = threadIdx.x;
    const int lane = tid & 63;
    const int wv   = tid >> 6;
    const int m    = lane & 15;
    const int q    = lane >> 4;

    const f16x8* bp  = (const f16x8*)ws;
    const float* cnb = ws + WS_CBN;

    const int p0 = blockIdx.x * 256;      // block: 256 consecutive positions
    const int b  = p0 >> 12;
    const int n0 = p0 & (VQ_HW - 1);
    const float* xw = x + (size_t)b * (VQ_D * VQ_HW) + n0 + wv * 64;

    // ---- A fragments (hi + scaled residual), 4 M-tiles, resident ----
    f16x8 Ah[4][2], Ra[4][2];
    #pragma unroll
    for (int tl = 0; tl < 4; ++tl)
        #pragma unroll
        for (int ks = 0; ks < 2; ++ks) {
            f16x8 h8, r8;
            #pragma unroll
            for (int j = 0; j < 8; ++j) {
                const int k = ks * 32 + q * 8 + j;
                const float v = xw[(size_t)k * VQ_HW + tl * 16 + m];
                const _Float16 vh = (_Float16)v;
                h8[j] = vh;
                r8[j] = (_Float16)((v - (float)vh) * SC);
            }
            Ah[tl][ks] = h8; Ra[tl][ks] = r8;
        }

    float d1[4][4], d2[4][4]; int k1[4][4];
    #pragma unroll
    for (int tl = 0; tl < 4; ++tl)
        #pragma unroll
        for (int r = 0; r < 4; ++r) { d1[tl][r] = 3.4e38f; d2[tl][r] = 3.4e38f; k1[tl][r] = 0; }

    const f32x4 zero4 = {0.f, 0.f, 0.f, 0.f};

    // ping-pong sets a (even ct) / b (odd ct)
    f16x8 B0a, B1a, R0a, R1a, B0b, B1b, R0b, R1b;
    float cva, cvb;
    PREFETCH(B0a, B1a, R0a, R1a, cva, 0)
    PREFETCH(B0b, B1b, R0b, R1b, cvb, 1)

    for (int ct = 0; ct < 64; ct += 2) {
        COMPUTE(B0a, B1a, R0a, R1a, cva, ct)
        {
            const int ctn = (ct + 2 < 64) ? ct + 2 : 62;
            PREFETCH(B0a, B1a, R0a, R1a, cva, ctn)
        }
        COMPUTE(B0b, B1b, R0b, R1b, cvb, ct + 1)
        {
            const int ctn = (ct + 3 < 64) ? ct + 3 : 63;
            PREFETCH(B0b, B1b, R0b, R1b, cvb, ctn)
        }
    }

    // ---- top-2 merge across the 16 code-columns (xor 1,2,4,8) ----
    #pragma unroll
    for (int off = 1; off < 16; off <<= 1)
        #pragma unroll
        for (int tl = 0; tl < 4; ++tl)
            #pragma unroll
            for (int r = 0; r < 4; ++r) {
                const float od1 = __shfl_xor(d1[tl][r], off, 64);
                const float od2 = __shfl_xor(d2[tl][r], off, 64);
                const int   ok1 = __shfl_xor(k1[tl][r], off, 64);
                const float nd2 = fminf(fmaxf(d1[tl][r], od1), fminf(d2[tl][r], od2));
                const bool  sw  = (od1 < d1[tl][r]) ||
                                  (od1 == d1[tl][r] && ok1 < k1[tl][r]);  // tie -> min k
                d1[tl][r] = sw ? od1 : d1[tl][r];
                k1[tl][r] = sw ? ok1 : k1[tl][r];
                d2[tl][r] = nd2;
            }

    if (m == 0) {
        #pragma unroll
        for (int tl = 0; tl < 4; ++tl)
            #pragma unroll
            for (int r = 0; r < 4; ++r) {
                const int li = wv * 64 + tl * 16 + q * 4 + r;
                sk[li]  = k1[tl][r];
                smg[li] = d2[tl][r] - d1[tl][r];
            }
    }
    __syncthreads();

    // ---- epilogue: indices, rescan flags, quantized scatter ----
    idx_out[p0 + tid] = (float)sk[tid];
    if (smg[tid] < EPS) {
        const int slot = atomicAdd((int*)ws + WS_CNT, 1);
        ((int*)ws)[WS_LIST + slot] = p0 + tid;
    }
    const int bk = sk[tid];
    const float4* cr = (const float4*)(cb + (size_t)bk * VQ_D);
    float* ob = out + (size_t)b * (VQ_D * VQ_HW) + n0 + tid;
    #pragma unroll
    for (int d4 = 0; d4 < 16; ++d4) {
        const float4 v = cr[d4];
        ob[(size_t)(d4 * 4 + 0) * VQ_HW] = v.x;
        ob[(size_t)(d4 * 4 + 1) * VQ_HW] = v.y;
        ob[(size_t)(d4 * 4 + 2) * VQ_HW] = v.z;
        ob[(size_t)(d4 * 4 + 3) * VQ_HW] = v.w;
    }
}

// ---------- rescan: exact f32 argmin for flagged positions ----------
__global__ __launch_bounds__(64)
void vq_rescan(const float* __restrict__ x,
               const float* __restrict__ cb,
               const float* __restrict__ ws,
               float* __restrict__ out,
               float* __restrict__ idx_out)
{
    __shared__ float xs[VQ_D];
    const int lane = threadIdx.x;
    const int cnt  = ((const int*)ws)[WS_CNT];
    const int* list = (const int*)ws + WS_LIST;
    const float*  cnb  = ws + WS_CBN;
    const float4* cbT4 = (const float4*)(ws + WS_CBT);

    for (int i = blockIdx.x; i < cnt; i += gridDim.x) {
        const int p = list[i];
        const int b = p >> 12, n = p & (VQ_HW - 1);
        xs[lane] = x[(size_t)b * (VQ_D * VQ_HW) + (size_t)lane * VQ_HW + n];
        __syncthreads();
        float4 xr[16];
        #pragma unroll
        for (int j = 0; j < 16; ++j) xr[j] = ((const float4*)xs)[j];

        float bd = 3.4e38f; int bk = 0;
        #pragma unroll 4
        for (int t = 0; t < 16; ++t) {
            const int code = t * 64 + lane;           // per-lane ascending
            float a0 = 0.f, a1 = 0.f, a2 = 0.f, a3 = 0.f;
            #pragma unroll
            for (int j4 = 0; j4 < 16; ++j4) {
                const float4 c = cbT4[j4 * 1024 + code];   // coalesced
                a0 = fmaf(xr[j4].x, c.x, a0); a1 = fmaf(xr[j4].y, c.y, a1);
                a2 = fmaf(xr[j4].z, c.z, a2); a3 = fmaf(xr[j4].w, c.w, a3);
            }
            const float dist = fmaf(-2.0f, (a0 + a1) + (a2 + a3), cnb[code]);
            if (dist < bd) { bd = dist; bk = code; }
        }
        #pragma unroll
        for (int off = 1; off < 64; off <<= 1) {      // min dist, tie -> min k
            const float od = __shfl_xor(bd, off, 64);
            const int   ok = __shfl_xor(bk, off, 64);
            if (od < bd || (od == bd && ok < bk)) { bd = od; bk = ok; }
        }
        out[(size_t)b * (VQ_D * VQ_HW) + (size_t)lane * VQ_HW + n] = cb[(size_t)bk * VQ_D + lane];
        if (lane == 0) idx_out[p] = (float)bk;
        __syncthreads();
    }
}

extern "C" void kernel_launch(void* const* d_in, const int* in_sizes, int n_in,
                              void* d_out, int out_size, void* d_ws, size_t ws_size,
                              hipStream_t stream) {
    const float* x  = (const float*)d_in[0];
    const float* cb = (const float*)d_in[1];
    float* out = (float*)d_out;
    float* idx = out + (size_t)VQ_NPOS * VQ_D;   // 8,388,608 floats in
    float* ws  = (float*)d_ws;                    // ~1.05 MB used

    vq_prep  <<<dim3(132),  dim3(256), 0, stream>>>(cb, ws);
    vq_main  <<<dim3(512),  dim3(256), 0, stream>>>(x, cb, ws, out, idx);
    vq_rescan<<<dim3(1024), dim3(64),  0, stream>>>(x, cb, ws, out, idx);
}